// Round 8
// baseline (333.932 us; speedup 1.0000x reference)
//
#include <hip/hip_runtime.h>

#define B_ 32
#define E_ 48
#define M_ 96
#define S_ 48
#define D_ 256
#define H_ 8
#define DPH_ 32
#define MAXL_ 16   // data bound: 1 guaranteed + Binomial(48,1/48) extras (max ~9)
#define JT_ 16     // j-tile width in pairs kernel
#define RT_ 16     // rows per prep block, types 0/1
#define RT2_ 8     // rows per prep block, type 2 (2x work/row -> equal block cost)

// ---------------------------------------------------------------------------
// K1: projections (R2 structure: scalar-W broadcast, no k-loop barriers).
// type 2 FIRST (v = men@Wv+bv then u[r,h,:] = v[r,h-slice]@Wo[h-slice]):
//   RT2_=8 rows/block -> 384 rowgroups x 2 mha = 768 blocks (2x work/row)
// type 1 (k = sen@Wk+bk, UNIQUE sentence rows B*S=1536): 96 x 2 = 192 blocks
// type 0 (q = ent@Wq+bq -> qh/qt): 96 x 2 = 192 blocks
// Grid = 1152 equal-cost blocks. Blocks 0..11 also do the K0 bucket pass
// (consumer is pairs_kernel, two dispatches later).
__global__ __launch_bounds__(256) void prep_kernel(
    const float* __restrict__ ent, const float* __restrict__ men,
    const float* __restrict__ sen, const int* __restrict__ info,
    const float* __restrict__ W1, const float* __restrict__ b1,
    const float* __restrict__ W2, const float* __restrict__ b2,
    float* __restrict__ qh, float* __restrict__ qt,
    float* __restrict__ k1, float* __restrict__ k2,
    float* __restrict__ u1, float* __restrict__ u2,
    int* __restrict__ cnt, int* __restrict__ lst) {
    __shared__ float a[RT_][D_];
    int bx = blockIdx.x;
    int tid = threadIdx.x;

    // ---- merged K0: bucket mentions by global entity id (12 blocks) ------
    if (bx < 12) {
        int g = bx * 256 + tid;                  // < 3072 = B*M
        int e = info[g * 6];
        int pos = atomicAdd(&cnt[e], 1);
        if (pos < MAXL_) lst[e * MAXL_ + pos] = g % M_;
    }

    int type, rg, mha;
    if (bx < 768) { type = 2; rg = bx >> 1; mha = bx & 1; }
    else if (bx < 960) { type = 1; rg = (bx - 768) >> 1; mha = bx & 1; }
    else { type = 0; rg = (bx - 960) >> 1; mha = bx & 1; }

    const float* Wb = mha ? W2 : W1;
    const float* bb = mha ? b2 : b1;
    const float* W = Wb + (size_t)type * D_ * D_;
    int tx = tid & 127, ty = tid >> 7;

    if (type == 2) {
        // ---- type 2: 8 rows, 4 rows per thread -------------------------
        int rowbase = rg * RT2_;
        for (int r = 0; r < RT2_; ++r)
            a[r][tid] = men[(size_t)(rowbase + r) * D_ + tid];
        __syncthreads();

        int r0 = ty * 4;
        float acc0[4], acc1[4];
        {
            float bv0 = bb[2 * D_ + tx], bv1 = bb[2 * D_ + tx + 128];
#pragma unroll
            for (int i = 0; i < 4; ++i) { acc0[i] = bv0; acc1[i] = bv1; }
        }
        for (int k = 0; k < D_; k += 4) {
            float wA0 = W[(size_t)k * D_ + tx],       wB0 = W[(size_t)k * D_ + tx + 128];
            float wA1 = W[(size_t)(k + 1) * D_ + tx], wB1 = W[(size_t)(k + 1) * D_ + tx + 128];
            float wA2 = W[(size_t)(k + 2) * D_ + tx], wB2 = W[(size_t)(k + 2) * D_ + tx + 128];
            float wA3 = W[(size_t)(k + 3) * D_ + tx], wB3 = W[(size_t)(k + 3) * D_ + tx + 128];
#pragma unroll
            for (int i = 0; i < 4; ++i) {
                float4 av = *(const float4*)&a[r0 + i][k];
                acc0[i] = fmaf(av.x, wA0, acc0[i]); acc1[i] = fmaf(av.x, wB0, acc1[i]);
                acc0[i] = fmaf(av.y, wA1, acc0[i]); acc1[i] = fmaf(av.y, wB1, acc1[i]);
                acc0[i] = fmaf(av.z, wA2, acc0[i]); acc1[i] = fmaf(av.z, wB2, acc1[i]);
                acc0[i] = fmaf(av.w, wA3, acc0[i]); acc1[i] = fmaf(av.w, wB3, acc1[i]);
            }
        }
        __syncthreads();  // all reads of a done
#pragma unroll
        for (int i = 0; i < 4; ++i) {
            a[r0 + i][tx] = acc0[i];
            a[r0 + i][tx + 128] = acc1[i];
        }
        __syncthreads();
        const float* Wo = Wb + (size_t)3 * D_ * D_;
        float* u = mha ? u2 : u1;
        for (int h = 0; h < H_; ++h) {
#pragma unroll
            for (int i = 0; i < 4; ++i) { acc0[i] = 0.f; acc1[i] = 0.f; }
            for (int k = 0; k < DPH_; k += 4) {
                int kk = h * DPH_ + k;
                float wA0 = Wo[(size_t)kk * D_ + tx],       wB0 = Wo[(size_t)kk * D_ + tx + 128];
                float wA1 = Wo[(size_t)(kk + 1) * D_ + tx], wB1 = Wo[(size_t)(kk + 1) * D_ + tx + 128];
                float wA2 = Wo[(size_t)(kk + 2) * D_ + tx], wB2 = Wo[(size_t)(kk + 2) * D_ + tx + 128];
                float wA3 = Wo[(size_t)(kk + 3) * D_ + tx], wB3 = Wo[(size_t)(kk + 3) * D_ + tx + 128];
#pragma unroll
                for (int i = 0; i < 4; ++i) {
                    float4 vv = *(const float4*)&a[r0 + i][kk & 255];
                    acc0[i] = fmaf(vv.x, wA0, acc0[i]); acc1[i] = fmaf(vv.x, wB0, acc1[i]);
                    acc0[i] = fmaf(vv.y, wA1, acc0[i]); acc1[i] = fmaf(vv.y, wB1, acc1[i]);
                    acc0[i] = fmaf(vv.z, wA2, acc0[i]); acc1[i] = fmaf(vv.z, wB2, acc1[i]);
                    acc0[i] = fmaf(vv.w, wA3, acc0[i]); acc1[i] = fmaf(vv.w, wB3, acc1[i]);
                }
            }
#pragma unroll
            for (int i = 0; i < 4; ++i) {
                u[((size_t)(rowbase + r0 + i) * H_ + h) * D_ + tx] = acc0[i];
                u[((size_t)(rowbase + r0 + i) * H_ + h) * D_ + tx + 128] = acc1[i];
            }
        }
        return;
    }

    // ---- types 0/1: 16 rows, 8 rows per thread --------------------------
    int rowbase = rg * RT_;
    if (type == 0) {
        for (int r = tid >> 7; r < RT_; r += 2)
            a[r][tid & 127] = ent[(size_t)(rowbase + r) * D_ + (tid & 127)];
        for (int r = tid >> 7; r < RT_; r += 2)
            a[r][(tid & 127) + 128] = ent[(size_t)(rowbase + r) * D_ + (tid & 127) + 128];
    } else {
        // unique sentence rows (dedup: B*S rows, not B*M gathered)
        for (int r = 0; r < RT_; ++r)
            a[r][tid] = sen[(size_t)(rowbase + r) * D_ + tid];
    }
    __syncthreads();

    int r0 = ty * 8;
    float acc0[8], acc1[8];
    {
        float bv0 = bb[type * D_ + tx], bv1 = bb[type * D_ + tx + 128];
#pragma unroll
        for (int i = 0; i < 8; ++i) { acc0[i] = bv0; acc1[i] = bv1; }
    }
    for (int k = 0; k < D_; k += 4) {
        float wA0 = W[(size_t)k * D_ + tx],       wB0 = W[(size_t)k * D_ + tx + 128];
        float wA1 = W[(size_t)(k + 1) * D_ + tx], wB1 = W[(size_t)(k + 1) * D_ + tx + 128];
        float wA2 = W[(size_t)(k + 2) * D_ + tx], wB2 = W[(size_t)(k + 2) * D_ + tx + 128];
        float wA3 = W[(size_t)(k + 3) * D_ + tx], wB3 = W[(size_t)(k + 3) * D_ + tx + 128];
#pragma unroll
        for (int i = 0; i < 8; ++i) {
            float4 av = *(const float4*)&a[r0 + i][k];
            acc0[i] = fmaf(av.x, wA0, acc0[i]); acc1[i] = fmaf(av.x, wB0, acc1[i]);
            acc0[i] = fmaf(av.y, wA1, acc0[i]); acc1[i] = fmaf(av.y, wB1, acc1[i]);
            acc0[i] = fmaf(av.z, wA2, acc0[i]); acc1[i] = fmaf(av.z, wB2, acc1[i]);
            acc0[i] = fmaf(av.w, wA3, acc0[i]); acc1[i] = fmaf(av.w, wB3, acc1[i]);
        }
    }

    float* o = (type == 0) ? (mha ? qt : qh) : (mha ? k2 : k1);
#pragma unroll
    for (int i = 0; i < 8; ++i) {
        o[(size_t)(rowbase + r0 + i) * D_ + tx] = acc0[i];
        o[(size_t)(rowbase + r0 + i) * D_ + tx + 128] = acc1[i];
    }
}

// ---------------------------------------------------------------------------
// K2: scores. Block per (b, h, which). k-tile holds the 48 UNIQUE sentence
// projections; per-mention rows resolved through sid_local (LDS broadcast on
// duplicates). Writes ES[which][b][h][m][q] (q inner).
__global__ __launch_bounds__(256) void scores_kernel(
    const float* __restrict__ qh, const float* __restrict__ qt,
    const float* __restrict__ k1, const float* __restrict__ k2,
    const int* __restrict__ info,
    float* __restrict__ ES) {
    int b = blockIdx.x, h = blockIdx.y, which = blockIdx.z;
    int tid = threadIdx.x;
    const float* q = (which ? qt : qh) + (size_t)b * E_ * D_ + h * DPH_;
    const float* kk = (which ? k2 : k1) + (size_t)b * S_ * D_ + h * DPH_;
    float* ESb = ES + (((size_t)which * B_ + b) * H_ + h) * (M_ * E_);

    __shared__ float qs[E_][DPH_ + 2];
    __shared__ float ks[S_][DPH_ + 2];
    __shared__ float Sb[E_][M_ + 2];
    __shared__ float mx[E_];
    __shared__ int sidl[M_];

    for (int idx = tid; idx < E_ * DPH_; idx += 256) {
        int r = idx >> 5, c = idx & 31;
        qs[r][c] = q[(size_t)r * D_ + c];
    }
    for (int idx = tid; idx < S_ * DPH_; idx += 256) {
        int r = idx >> 5, c = idx & 31;
        ks[r][c] = kk[(size_t)r * D_ + c];
    }
    if (tid < M_) sidl[tid] = info[(b * M_ + tid) * 6 + 4] - b * S_;
    __syncthreads();
#pragma unroll
    for (int it = 0; it < 18; ++it) {            // 18*256 = 4608 = E*M
        int pair = tid + it * 256;
        int qi = pair / 96, m = pair % 96;
        int sr = sidl[m];
        float acc = 0.f;
#pragma unroll
        for (int c = 0; c < DPH_; c += 2) {
            float2 qv = *(const float2*)&qs[qi][c];
            float2 kv = *(const float2*)&ks[sr][c];
            acc = fmaf(qv.x, kv.x, acc);
            acc = fmaf(qv.y, kv.y, acc);
        }
        Sb[qi][m] = acc * 0.17677669529663687f;  // 1/sqrt(32)
    }
    __syncthreads();
    if (tid < E_) {
        float mm = -1e30f;
        for (int m = 0; m < M_; ++m) mm = fmaxf(mm, Sb[tid][m]);
        mx[tid] = mm;
    }
    __syncthreads();
    for (int idx = tid; idx < E_ * M_; idx += 256) {
        int qi = idx % E_, m = idx / E_;
        ESb[m * E_ + qi] = __expf(Sb[qi][m] - mx[qi]);
    }
}

// ---------------------------------------------------------------------------
// K3: one block per (me, b) handling BOTH which planes (halves barrier count
// per output, doubles FMA-loop ILP, shares ent residual loads + lst).
// 48 output rows per plane in 3 register-blocked tiles of JT_=16.
__global__ __launch_bounds__(256) void pairs_kernel(
    const int* __restrict__ cnt_arr, const int* __restrict__ lst_arr,
    const float* __restrict__ ES,
    const float* __restrict__ u1, const float* __restrict__ u2,
    const float* __restrict__ ent,
    const float* __restrict__ bo1, const float* __restrict__ bo2,
    const float* __restrict__ ln1, const float* __restrict__ ln2,
    float* __restrict__ out) {
    int tid = threadIdx.x;
    int me = blockIdx.x;
    int b = blockIdx.y;

    const float* ESb0 = ES + ((size_t)b) * (H_ * M_ * E_);
    const float* ESb1 = ES + ((size_t)(B_ + b)) * (H_ * M_ * E_);
    float* outb0 = out + ((size_t)b) * E_ * E_ * D_;
    float* outb1 = out + ((size_t)(B_ + b)) * E_ * E_ * D_;

    __shared__ int lst[MAXL_];
    __shared__ float wj[2][MAXL_ * H_][JT_];   // 16 KB
    __shared__ float dinv_s[2][H_ * JT_];      // 1 KB
    __shared__ float xbuf[2 * JT_][D_ + 4];    // 33.3 KB
    __shared__ int cnt_s;

    if (tid == 0) cnt_s = min(cnt_arr[b * E_ + me], MAXL_);
    if (tid < MAXL_) lst[tid] = lst_arr[(b * E_ + me) * MAXL_ + tid];
    __syncthreads();
    int cnt = cnt_s;
    int K = cnt * H_;

    float bv0 = bo1[tid], bv1 = bo2[tid];
    int wave = tid >> 6, lane = tid & 63;

    for (int j0 = 0; j0 < E_; j0 += JT_) {
        // gather exp-scores for BOTH planes: coalesced float4 rows of 16 q's
        for (int idx = tid; idx < K * 4; idx += 256) {
            int k = idx >> 2, j4 = (idx & 3) * 4;
            int pos = k >> 3, h = k & 7;
            *(float4*)&wj[0][k][j4] =
                *(const float4*)&ESb0[(size_t)(h * M_ + lst[pos]) * E_ + j0 + j4];
        }
        for (int idx = tid; idx < K * 4; idx += 256) {
            int k = idx >> 2, j4 = (idx & 3) * 4;
            int pos = k >> 3, h = k & 7;
            *(float4*)&wj[1][k][j4] =
                *(const float4*)&ESb1[(size_t)(h * M_ + lst[pos]) * E_ + j0 + j4];
        }
        __syncthreads();
        {   // 256 threads = 2 planes x 8 h x 16 j -- exact cover
            int wh = tid >> 7, hj = tid & 127;
            int h = hj >> 4, j = hj & 15;
            float s = 0.f;
            for (int pos = 0; pos < cnt; ++pos) s += wj[wh][pos * 8 + h][j];
            dinv_s[wh][hj] = 1.0f / s;
        }
        __syncthreads();
        for (int idx = tid; idx < 2 * K * JT_; idx += 256) {
            int wh = idx >= K * JT_;
            int r = idx - wh * (K * JT_);
            int k = r >> 4, j = r & 15;
            wj[wh][k][j] *= dinv_s[wh][((k & 7) << 4) + j];
        }
        __syncthreads();

        // acc[wh][j] += w[wh][k][j] * u_wh[k][tid] -- 2x independent loads
        float acc0[JT_], acc1[JT_];
#pragma unroll
        for (int j = 0; j < JT_; ++j) { acc0[j] = 0.f; acc1[j] = 0.f; }
        for (int pos = 0; pos < cnt; ++pos) {
            const float* ub0 = u1 + (size_t)(b * M_ + lst[pos]) * (H_ * D_) + tid;
            const float* ub1 = u2 + (size_t)(b * M_ + lst[pos]) * (H_ * D_) + tid;
#pragma unroll
            for (int h = 0; h < H_; ++h) {
                float uv0 = ub0[(size_t)h * D_];
                float uv1 = ub1[(size_t)h * D_];
                const float* wb0 = wj[0][pos * 8 + h];
                const float* wb1 = wj[1][pos * 8 + h];
                float4 a0 = *(const float4*)&wb0[0];
                float4 a1 = *(const float4*)&wb0[4];
                float4 a2 = *(const float4*)&wb0[8];
                float4 a3 = *(const float4*)&wb0[12];
                float4 c0 = *(const float4*)&wb1[0];
                float4 c1 = *(const float4*)&wb1[4];
                float4 c2 = *(const float4*)&wb1[8];
                float4 c3 = *(const float4*)&wb1[12];
                acc0[0]  = fmaf(a0.x, uv0, acc0[0]);
                acc0[1]  = fmaf(a0.y, uv0, acc0[1]);
                acc0[2]  = fmaf(a0.z, uv0, acc0[2]);
                acc0[3]  = fmaf(a0.w, uv0, acc0[3]);
                acc0[4]  = fmaf(a1.x, uv0, acc0[4]);
                acc0[5]  = fmaf(a1.y, uv0, acc0[5]);
                acc0[6]  = fmaf(a1.z, uv0, acc0[6]);
                acc0[7]  = fmaf(a1.w, uv0, acc0[7]);
                acc0[8]  = fmaf(a2.x, uv0, acc0[8]);
                acc0[9]  = fmaf(a2.y, uv0, acc0[9]);
                acc0[10] = fmaf(a2.z, uv0, acc0[10]);
                acc0[11] = fmaf(a2.w, uv0, acc0[11]);
                acc0[12] = fmaf(a3.x, uv0, acc0[12]);
                acc0[13] = fmaf(a3.y, uv0, acc0[13]);
                acc0[14] = fmaf(a3.z, uv0, acc0[14]);
                acc0[15] = fmaf(a3.w, uv0, acc0[15]);
                acc1[0]  = fmaf(c0.x, uv1, acc1[0]);
                acc1[1]  = fmaf(c0.y, uv1, acc1[1]);
                acc1[2]  = fmaf(c0.z, uv1, acc1[2]);
                acc1[3]  = fmaf(c0.w, uv1, acc1[3]);
                acc1[4]  = fmaf(c1.x, uv1, acc1[4]);
                acc1[5]  = fmaf(c1.y, uv1, acc1[5]);
                acc1[6]  = fmaf(c1.z, uv1, acc1[6]);
                acc1[7]  = fmaf(c1.w, uv1, acc1[7]);
                acc1[8]  = fmaf(c2.x, uv1, acc1[8]);
                acc1[9]  = fmaf(c2.y, uv1, acc1[9]);
                acc1[10] = fmaf(c2.z, uv1, acc1[10]);
                acc1[11] = fmaf(c2.w, uv1, acc1[11]);
                acc1[12] = fmaf(c3.x, uv1, acc1[12]);
                acc1[13] = fmaf(c3.y, uv1, acc1[13]);
                acc1[14] = fmaf(c3.z, uv1, acc1[14]);
                acc1[15] = fmaf(c3.w, uv1, acc1[15]);
            }
        }

        // stage x = residual + bias + ctx for both planes (ent loaded once)
#pragma unroll
        for (int j = 0; j < JT_; ++j) {
            float e = ent[(size_t)(b * E_ + j0 + j) * D_ + tid];
            xbuf[j][tid] = e + bv0 + acc0[j];
            xbuf[JT_ + j][tid] = e + bv1 + acc1[j];
        }
        __syncthreads();

        // LayerNorm: 32 rows over 4 waves, shuffle reduction, float4 store
        for (int jj = wave; jj < 2 * JT_; jj += 4) {
            int wh = jj >= JT_;
            int j = jj - wh * JT_;
            const float* ln = wh ? ln2 : ln1;
            float4 xv = *(const float4*)&xbuf[jj][lane * 4];
            float s = xv.x + xv.y + xv.z + xv.w;
            float sq = xv.x * xv.x + xv.y * xv.y + xv.z * xv.z + xv.w * xv.w;
#pragma unroll
            for (int off = 32; off > 0; off >>= 1) {
                s += __shfl_xor(s, off);
                sq += __shfl_xor(sq, off);
            }
            float mu = s * (1.0f / D_);
            float var = sq * (1.0f / D_) - mu * mu;
            float inv = rsqrtf(fmaxf(var, 0.f) + 1e-5f);
            float4 g = *(const float4*)&ln[lane * 4];
            float4 be = *(const float4*)&ln[D_ + lane * 4];
            float4 y;
            y.x = (xv.x - mu) * inv * g.x + be.x;
            y.y = (xv.y - mu) * inv * g.y + be.y;
            y.z = (xv.z - mu) * inv * g.z + be.z;
            y.w = (xv.w - mu) * inv * g.w + be.w;
            int o = j0 + j;
            size_t orow = wh ? ((size_t)o * E_ + me) : ((size_t)me * E_ + o);
            float* outb = wh ? outb1 : outb0;
            *(float4*)&outb[orow * D_ + lane * 4] = y;
        }
        __syncthreads();
    }
}

// ---------------------------------------------------------------------------
extern "C" void kernel_launch(void* const* d_in, const int* in_sizes, int n_in,
                              void* d_out, int out_size, void* d_ws, size_t ws_size,
                              hipStream_t stream) {
    const int* info = (const int*)d_in[0];
    const float* ent = (const float*)d_in[2];
    const float* men = (const float*)d_in[3];
    const float* sen = (const float*)d_in[4];
    const float* W1 = (const float*)d_in[5];
    const float* b1 = (const float*)d_in[6];
    const float* ln1 = (const float*)d_in[7];
    const float* W2 = (const float*)d_in[8];
    const float* b2 = (const float*)d_in[9];
    const float* ln2 = (const float*)d_in[10];
    float* out = (float*)d_out;

    float* ws = (float*)d_ws;
    size_t off = 0;
    float* qh = ws + off; off += (size_t)B_ * E_ * D_;
    float* qt = ws + off; off += (size_t)B_ * E_ * D_;
    float* k1 = ws + off; off += (size_t)B_ * S_ * D_;
    float* k2 = ws + off; off += (size_t)B_ * S_ * D_;
    float* u1 = ws + off; off += (size_t)B_ * M_ * H_ * D_;
    float* u2 = ws + off; off += (size_t)B_ * M_ * H_ * D_;
    float* ES = ws + off; off += (size_t)2 * B_ * H_ * M_ * E_;
    int* cnt = (int*)(ws + off); off += B_ * E_;
    int* lst = (int*)(ws + off); off += (size_t)B_ * E_ * MAXL_;

    hipMemsetAsync(cnt, 0, B_ * E_ * sizeof(int), stream);
    prep_kernel<<<1152, 256, 0, stream>>>(
        ent, men, sen, info, W1, b1, W2, b2, qh, qt, k1, k2, u1, u2, cnt, lst);
    scores_kernel<<<dim3(B_, H_, 2), 256, 0, stream>>>(qh, qt, k1, k2, info, ES);
    pairs_kernel<<<dim3(E_, B_), 256, 0, stream>>>(
        cnt, lst, ES, u1, u2, ent,
        b1 + 3 * D_, b2 + 3 * D_, ln1, ln2, out);
}

// Round 9
// 322.076 us; speedup vs baseline: 1.0368x; 1.0368x over previous
//
#include <hip/hip_runtime.h>

#define B_ 32
#define E_ 48
#define M_ 96
#define S_ 48
#define D_ 256
#define H_ 8
#define DPH_ 32
#define MAXL_ 16   // data bound: 1 guaranteed + Binomial(48,1/48) extras (max ~9)
#define JT_ 16     // j-tile width in pairs kernel (LN staging)
#define RT_ 16     // rows per prep block, types 0/1
#define RT2_ 8     // rows per prep block, type 2 (2x work/row -> equal block cost)

// ---------------------------------------------------------------------------
// K1: projections (R2 structure: scalar-W broadcast, no k-loop barriers).
// type 2 FIRST (v = men@Wv+bv then u[r,h,:] = v[r,h-slice]@Wo[h-slice]):
//   RT2_=8 rows/block -> 384 rowgroups x 2 mha = 768 blocks (2x work/row)
// type 1 (k = sen@Wk+bk, UNIQUE sentence rows B*S=1536): 96 x 2 = 192 blocks
// type 0 (q = ent@Wq+bq -> qh/qt): 96 x 2 = 192 blocks
// Grid = 1152 equal-cost blocks. Blocks 0..11 also do the K0 bucket pass
// (consumer is pairs_kernel, two dispatches later).
__global__ __launch_bounds__(256) void prep_kernel(
    const float* __restrict__ ent, const float* __restrict__ men,
    const float* __restrict__ sen, const int* __restrict__ info,
    const float* __restrict__ W1, const float* __restrict__ b1,
    const float* __restrict__ W2, const float* __restrict__ b2,
    float* __restrict__ qh, float* __restrict__ qt,
    float* __restrict__ k1, float* __restrict__ k2,
    float* __restrict__ u1, float* __restrict__ u2,
    int* __restrict__ cnt, int* __restrict__ lst) {
    __shared__ float a[RT_][D_];
    int bx = blockIdx.x;
    int tid = threadIdx.x;

    // ---- merged K0: bucket mentions by global entity id (12 blocks) ------
    if (bx < 12) {
        int g = bx * 256 + tid;                  // < 3072 = B*M
        int e = info[g * 6];
        int pos = atomicAdd(&cnt[e], 1);
        if (pos < MAXL_) lst[e * MAXL_ + pos] = g % M_;
    }

    int type, rg, mha;
    if (bx < 768) { type = 2; rg = bx >> 1; mha = bx & 1; }
    else if (bx < 960) { type = 1; rg = (bx - 768) >> 1; mha = bx & 1; }
    else { type = 0; rg = (bx - 960) >> 1; mha = bx & 1; }

    const float* Wb = mha ? W2 : W1;
    const float* bb = mha ? b2 : b1;
    const float* W = Wb + (size_t)type * D_ * D_;
    int tx = tid & 127, ty = tid >> 7;

    if (type == 2) {
        // ---- type 2: 8 rows, 4 rows per thread -------------------------
        int rowbase = rg * RT2_;
        for (int r = 0; r < RT2_; ++r)
            a[r][tid] = men[(size_t)(rowbase + r) * D_ + tid];
        __syncthreads();

        int r0 = ty * 4;
        float acc0[4], acc1[4];
        {
            float bv0 = bb[2 * D_ + tx], bv1 = bb[2 * D_ + tx + 128];
#pragma unroll
            for (int i = 0; i < 4; ++i) { acc0[i] = bv0; acc1[i] = bv1; }
        }
        for (int k = 0; k < D_; k += 4) {
            float wA0 = W[(size_t)k * D_ + tx],       wB0 = W[(size_t)k * D_ + tx + 128];
            float wA1 = W[(size_t)(k + 1) * D_ + tx], wB1 = W[(size_t)(k + 1) * D_ + tx + 128];
            float wA2 = W[(size_t)(k + 2) * D_ + tx], wB2 = W[(size_t)(k + 2) * D_ + tx + 128];
            float wA3 = W[(size_t)(k + 3) * D_ + tx], wB3 = W[(size_t)(k + 3) * D_ + tx + 128];
#pragma unroll
            for (int i = 0; i < 4; ++i) {
                float4 av = *(const float4*)&a[r0 + i][k];
                acc0[i] = fmaf(av.x, wA0, acc0[i]); acc1[i] = fmaf(av.x, wB0, acc1[i]);
                acc0[i] = fmaf(av.y, wA1, acc0[i]); acc1[i] = fmaf(av.y, wB1, acc1[i]);
                acc0[i] = fmaf(av.z, wA2, acc0[i]); acc1[i] = fmaf(av.z, wB2, acc1[i]);
                acc0[i] = fmaf(av.w, wA3, acc0[i]); acc1[i] = fmaf(av.w, wB3, acc1[i]);
            }
        }
        __syncthreads();  // all reads of a done
#pragma unroll
        for (int i = 0; i < 4; ++i) {
            a[r0 + i][tx] = acc0[i];
            a[r0 + i][tx + 128] = acc1[i];
        }
        __syncthreads();
        const float* Wo = Wb + (size_t)3 * D_ * D_;
        float* u = mha ? u2 : u1;
        for (int h = 0; h < H_; ++h) {
#pragma unroll
            for (int i = 0; i < 4; ++i) { acc0[i] = 0.f; acc1[i] = 0.f; }
            for (int k = 0; k < DPH_; k += 4) {
                int kk = h * DPH_ + k;
                float wA0 = Wo[(size_t)kk * D_ + tx],       wB0 = Wo[(size_t)kk * D_ + tx + 128];
                float wA1 = Wo[(size_t)(kk + 1) * D_ + tx], wB1 = Wo[(size_t)(kk + 1) * D_ + tx + 128];
                float wA2 = Wo[(size_t)(kk + 2) * D_ + tx], wB2 = Wo[(size_t)(kk + 2) * D_ + tx + 128];
                float wA3 = Wo[(size_t)(kk + 3) * D_ + tx], wB3 = Wo[(size_t)(kk + 3) * D_ + tx + 128];
#pragma unroll
                for (int i = 0; i < 4; ++i) {
                    float4 vv = *(const float4*)&a[r0 + i][kk & 255];
                    acc0[i] = fmaf(vv.x, wA0, acc0[i]); acc1[i] = fmaf(vv.x, wB0, acc1[i]);
                    acc0[i] = fmaf(vv.y, wA1, acc0[i]); acc1[i] = fmaf(vv.y, wB1, acc1[i]);
                    acc0[i] = fmaf(vv.z, wA2, acc0[i]); acc1[i] = fmaf(vv.z, wB2, acc1[i]);
                    acc0[i] = fmaf(vv.w, wA3, acc0[i]); acc1[i] = fmaf(vv.w, wB3, acc1[i]);
                }
            }
#pragma unroll
            for (int i = 0; i < 4; ++i) {
                u[((size_t)(rowbase + r0 + i) * H_ + h) * D_ + tx] = acc0[i];
                u[((size_t)(rowbase + r0 + i) * H_ + h) * D_ + tx + 128] = acc1[i];
            }
        }
        return;
    }

    // ---- types 0/1: 16 rows, 8 rows per thread --------------------------
    int rowbase = rg * RT_;
    if (type == 0) {
        for (int r = tid >> 7; r < RT_; r += 2)
            a[r][tid & 127] = ent[(size_t)(rowbase + r) * D_ + (tid & 127)];
        for (int r = tid >> 7; r < RT_; r += 2)
            a[r][(tid & 127) + 128] = ent[(size_t)(rowbase + r) * D_ + (tid & 127) + 128];
    } else {
        // unique sentence rows (dedup: B*S rows, not B*M gathered)
        for (int r = 0; r < RT_; ++r)
            a[r][tid] = sen[(size_t)(rowbase + r) * D_ + tid];
    }
    __syncthreads();

    int r0 = ty * 8;
    float acc0[8], acc1[8];
    {
        float bv0 = bb[type * D_ + tx], bv1 = bb[type * D_ + tx + 128];
#pragma unroll
        for (int i = 0; i < 8; ++i) { acc0[i] = bv0; acc1[i] = bv1; }
    }
    for (int k = 0; k < D_; k += 4) {
        float wA0 = W[(size_t)k * D_ + tx],       wB0 = W[(size_t)k * D_ + tx + 128];
        float wA1 = W[(size_t)(k + 1) * D_ + tx], wB1 = W[(size_t)(k + 1) * D_ + tx + 128];
        float wA2 = W[(size_t)(k + 2) * D_ + tx], wB2 = W[(size_t)(k + 2) * D_ + tx + 128];
        float wA3 = W[(size_t)(k + 3) * D_ + tx], wB3 = W[(size_t)(k + 3) * D_ + tx + 128];
#pragma unroll
        for (int i = 0; i < 8; ++i) {
            float4 av = *(const float4*)&a[r0 + i][k];
            acc0[i] = fmaf(av.x, wA0, acc0[i]); acc1[i] = fmaf(av.x, wB0, acc1[i]);
            acc0[i] = fmaf(av.y, wA1, acc0[i]); acc1[i] = fmaf(av.y, wB1, acc1[i]);
            acc0[i] = fmaf(av.z, wA2, acc0[i]); acc1[i] = fmaf(av.z, wB2, acc1[i]);
            acc0[i] = fmaf(av.w, wA3, acc0[i]); acc1[i] = fmaf(av.w, wB3, acc1[i]);
        }
    }

    float* o = (type == 0) ? (mha ? qt : qh) : (mha ? k2 : k1);
#pragma unroll
    for (int i = 0; i < 8; ++i) {
        o[(size_t)(rowbase + r0 + i) * D_ + tx] = acc0[i];
        o[(size_t)(rowbase + r0 + i) * D_ + tx + 128] = acc1[i];
    }
}

// ---------------------------------------------------------------------------
// K2: scores. Block per (b, h, which). k-tile holds the 48 UNIQUE sentence
// projections; per-mention rows resolved through sid_local (LDS broadcast on
// duplicates). Writes ES[which][b][h][m][q] (q inner).
__global__ __launch_bounds__(256) void scores_kernel(
    const float* __restrict__ qh, const float* __restrict__ qt,
    const float* __restrict__ k1, const float* __restrict__ k2,
    const int* __restrict__ info,
    float* __restrict__ ES) {
    int b = blockIdx.x, h = blockIdx.y, which = blockIdx.z;
    int tid = threadIdx.x;
    const float* q = (which ? qt : qh) + (size_t)b * E_ * D_ + h * DPH_;
    const float* kk = (which ? k2 : k1) + (size_t)b * S_ * D_ + h * DPH_;
    float* ESb = ES + (((size_t)which * B_ + b) * H_ + h) * (M_ * E_);

    __shared__ float qs[E_][DPH_ + 2];
    __shared__ float ks[S_][DPH_ + 2];
    __shared__ float Sb[E_][M_ + 2];
    __shared__ float mx[E_];
    __shared__ int sidl[M_];

    for (int idx = tid; idx < E_ * DPH_; idx += 256) {
        int r = idx >> 5, c = idx & 31;
        qs[r][c] = q[(size_t)r * D_ + c];
    }
    for (int idx = tid; idx < S_ * DPH_; idx += 256) {
        int r = idx >> 5, c = idx & 31;
        ks[r][c] = kk[(size_t)r * D_ + c];
    }
    if (tid < M_) sidl[tid] = info[(b * M_ + tid) * 6 + 4] - b * S_;
    __syncthreads();
#pragma unroll
    for (int it = 0; it < 18; ++it) {            // 18*256 = 4608 = E*M
        int pair = tid + it * 256;
        int qi = pair / 96, m = pair % 96;
        int sr = sidl[m];
        float acc = 0.f;
#pragma unroll
        for (int c = 0; c < DPH_; c += 2) {
            float2 qv = *(const float2*)&qs[qi][c];
            float2 kv = *(const float2*)&ks[sr][c];
            acc = fmaf(qv.x, kv.x, acc);
            acc = fmaf(qv.y, kv.y, acc);
        }
        Sb[qi][m] = acc * 0.17677669529663687f;  // 1/sqrt(32)
    }
    __syncthreads();
    if (tid < E_) {
        float mm = -1e30f;
        for (int m = 0; m < M_; ++m) mm = fmaxf(mm, Sb[tid][m]);
        mx[tid] = mm;
    }
    __syncthreads();
    for (int idx = tid; idx < E_ * M_; idx += 256) {
        int qi = idx % E_, m = idx / E_;
        ESb[m * E_ + qi] = __expf(Sb[qi][m] - mx[qi]);
    }
}

// ---------------------------------------------------------------------------
// K3: one block per (me, b, which). Full-width restructure: gather all 48 q
// of exp-scores once (wj[K][48]), dinv + scale ONCE (they don't depend on
// the j-tile), then one uninterrupted FMA pass with acc[48] (u read ONCE,
// wj reads are wave-broadcast), then 3x {stage 16 rows -> LayerNorm}.
// Barriers 15 -> 9; u global traffic 1/3 of R7. LDS ~42.5 KB.
__global__ __launch_bounds__(256) void pairs_kernel(
    const int* __restrict__ cnt_arr, const int* __restrict__ lst_arr,
    const float* __restrict__ ES,
    const float* __restrict__ u1, const float* __restrict__ u2,
    const float* __restrict__ ent,
    const float* __restrict__ bo1, const float* __restrict__ bo2,
    const float* __restrict__ ln1, const float* __restrict__ ln2,
    float* __restrict__ out) {
    int tid = threadIdx.x;
    int me = blockIdx.x;
    int b = blockIdx.y;
    int which = blockIdx.z;

    const float* ESb = ES + ((size_t)which * B_ + b) * (H_ * M_ * E_);
    const float* u = which ? u2 : u1;
    const float* bo = which ? bo2 : bo1;
    const float* ln = which ? ln2 : ln1;
    float* outb = out + ((size_t)which * B_ + b) * E_ * E_ * D_;

    __shared__ int lst[MAXL_];
    __shared__ float wj[MAXL_ * H_][E_];     // 24 KB (rows of all 48 q)
    __shared__ float dinv_s[H_][E_];         // 1.5 KB
    __shared__ float xbuf[JT_][D_ + 4];      // 16.6 KB
    __shared__ int cnt_s;

    if (tid == 0) cnt_s = min(cnt_arr[b * E_ + me], MAXL_);
    if (tid < MAXL_) lst[tid] = lst_arr[(b * E_ + me) * MAXL_ + tid];
    __syncthreads();
    int cnt = cnt_s;
    int K = cnt * H_;

    // ---- gather exp-scores: full 48-wide rows, coalesced float4 ----------
    for (int idx = tid; idx < K * 12; idx += 256) {
        int k = idx / 12, j4 = (idx % 12) * 4;
        int pos = k >> 3, h = k & 7;
        *(float4*)&wj[k][j4] =
            *(const float4*)&ESb[(size_t)(h * M_ + lst[pos]) * E_ + j4];
    }
    __syncthreads();

    // ---- softmax denominators for ALL (h, q) at once ---------------------
    for (int idx = tid; idx < H_ * E_; idx += 256) {
        int h = idx / E_, q = idx - (idx / E_) * E_;
        float s = 0.f;
        for (int pos = 0; pos < cnt; ++pos) s += wj[pos * 8 + h][q];
        dinv_s[h][q] = 1.0f / s;
    }
    __syncthreads();

    // ---- scale wj in place ----------------------------------------------
    for (int idx = tid; idx < K * E_; idx += 256) {
        int k = idx / E_, q = idx - (idx / E_) * E_;
        wj[k][q] *= dinv_s[k & 7][q];
    }
    __syncthreads();

    // ---- single FMA pass: acc[48], u read once ---------------------------
    float acc[E_];
#pragma unroll
    for (int j = 0; j < E_; ++j) acc[j] = 0.f;
    for (int pos = 0; pos < cnt; ++pos) {
        const float* ub = u + (size_t)(b * M_ + lst[pos]) * (H_ * D_) + tid;
#pragma unroll
        for (int h = 0; h < H_; ++h) {
            float uval = ub[(size_t)h * D_];
            const float* wb = wj[pos * 8 + h];
#pragma unroll
            for (int jq = 0; jq < E_; jq += 4) {
                float4 w = *(const float4*)&wb[jq];   // wave-broadcast
                acc[jq]     = fmaf(w.x, uval, acc[jq]);
                acc[jq + 1] = fmaf(w.y, uval, acc[jq + 1]);
                acc[jq + 2] = fmaf(w.z, uval, acc[jq + 2]);
                acc[jq + 3] = fmaf(w.w, uval, acc[jq + 3]);
            }
        }
    }

    // ---- epilogue: 3 tiles of {stage residual+bias+ctx -> LayerNorm} -----
    float bv = bo[tid];
    int wave = tid >> 6, lane = tid & 63;
#pragma unroll
    for (int t = 0; t < 3; ++t) {
        int j0 = t * JT_;
#pragma unroll
        for (int j = 0; j < JT_; ++j) {
            float e = ent[(size_t)(b * E_ + j0 + j) * D_ + tid];
            xbuf[j][tid] = e + bv + acc[j0 + j];
        }
        __syncthreads();
        for (int jj = wave; jj < JT_; jj += 4) {
            float4 xv = *(const float4*)&xbuf[jj][lane * 4];
            float s = xv.x + xv.y + xv.z + xv.w;
            float sq = xv.x * xv.x + xv.y * xv.y + xv.z * xv.z + xv.w * xv.w;
#pragma unroll
            for (int off = 32; off > 0; off >>= 1) {
                s += __shfl_xor(s, off);
                sq += __shfl_xor(sq, off);
            }
            float mu = s * (1.0f / D_);
            float var = sq * (1.0f / D_) - mu * mu;
            float inv = rsqrtf(fmaxf(var, 0.f) + 1e-5f);
            float4 g = *(const float4*)&ln[lane * 4];
            float4 be = *(const float4*)&ln[D_ + lane * 4];
            float4 y;
            y.x = (xv.x - mu) * inv * g.x + be.x;
            y.y = (xv.y - mu) * inv * g.y + be.y;
            y.z = (xv.z - mu) * inv * g.z + be.z;
            y.w = (xv.w - mu) * inv * g.w + be.w;
            int o = j0 + jj;
            size_t orow = which ? ((size_t)o * E_ + me) : ((size_t)me * E_ + o);
            *(float4*)&outb[orow * D_ + lane * 4] = y;
        }
        __syncthreads();
    }
}

// ---------------------------------------------------------------------------
extern "C" void kernel_launch(void* const* d_in, const int* in_sizes, int n_in,
                              void* d_out, int out_size, void* d_ws, size_t ws_size,
                              hipStream_t stream) {
    const int* info = (const int*)d_in[0];
    const float* ent = (const float*)d_in[2];
    const float* men = (const float*)d_in[3];
    const float* sen = (const float*)d_in[4];
    const float* W1 = (const float*)d_in[5];
    const float* b1 = (const float*)d_in[6];
    const float* ln1 = (const float*)d_in[7];
    const float* W2 = (const float*)d_in[8];
    const float* b2 = (const float*)d_in[9];
    const float* ln2 = (const float*)d_in[10];
    float* out = (float*)d_out;

    float* ws = (float*)d_ws;
    size_t off = 0;
    float* qh = ws + off; off += (size_t)B_ * E_ * D_;
    float* qt = ws + off; off += (size_t)B_ * E_ * D_;
    float* k1 = ws + off; off += (size_t)B_ * S_ * D_;
    float* k2 = ws + off; off += (size_t)B_ * S_ * D_;
    float* u1 = ws + off; off += (size_t)B_ * M_ * H_ * D_;
    float* u2 = ws + off; off += (size_t)B_ * M_ * H_ * D_;
    float* ES = ws + off; off += (size_t)2 * B_ * H_ * M_ * E_;
    int* cnt = (int*)(ws + off); off += B_ * E_;
    int* lst = (int*)(ws + off); off += (size_t)B_ * E_ * MAXL_;

    hipMemsetAsync(cnt, 0, B_ * E_ * sizeof(int), stream);
    prep_kernel<<<1152, 256, 0, stream>>>(
        ent, men, sen, info, W1, b1, W2, b2, qh, qt, k1, k2, u1, u2, cnt, lst);
    scores_kernel<<<dim3(B_, H_, 2), 256, 0, stream>>>(qh, qt, k1, k2, info, ES);
    pairs_kernel<<<dim3(E_, B_, 2), 256, 0, stream>>>(
        cnt, lst, ES, u1, u2, ent,
        b1 + 3 * D_, b2 + 3 * D_, ln1, ln2, out);
}